// Round 1
// baseline (1107.627 us; speedup 1.0000x reference)
//
#include <hip/hip_runtime.h>
#include <stdint.h>

typedef unsigned short u16;
typedef short bf16x8 __attribute__((ext_vector_type(8)));
typedef float f32x4 __attribute__((ext_vector_type(4)));

#define NB   256
#define NS   200
#define NHID 768
#define NHEAD 12
#define NDK  64
#define NK   64
#define NBH  (NB*NHEAD)   // 3072
#define NM   (NB*NS)      // 51200

__device__ __forceinline__ u16 f2b(float f){
  unsigned u = __builtin_bit_cast(unsigned, f);
  return (u16)((u + 0x7FFFu + ((u>>16)&1u)) >> 16);   // RNE, finite inputs
}
__device__ __forceinline__ bf16x8 pack8(const float* v){
  bf16x8 r;
#pragma unroll
  for (int i=0;i<8;i++) r[i] = (short)f2b(v[i]);
  return r;
}
__device__ __forceinline__ f32x4 mfma16(bf16x8 a, bf16x8 b, f32x4 c){
  return __builtin_amdgcn_mfma_f32_16x16x32_bf16(a, b, c, 0, 0, 0);
}

// ---------------- 1) fused QKV projection GEMM -------------------------------
// Y = x @ W.T + b  (M=51200, N=768, K=768), z selects {q,k,v}.
// q stored (B,NH,S,DK) bf16; k,v stored TRANSPOSED (B,NH,DK,S) bf16, mask applied.
__global__ __launch_bounds__(256) void qkv_kernel(
    const float* __restrict__ x,
    const float* __restrict__ Wq, const float* __restrict__ bq,
    const float* __restrict__ Wk, const float* __restrict__ bk,
    const float* __restrict__ Wv, const float* __restrict__ bv,
    const float* __restrict__ mask,
    u16* __restrict__ qb, u16* __restrict__ kTb, u16* __restrict__ vTb)
{
  __shared__ u16 Al[128*40];   // ld=40 elems (80B): b128 frag reads 2-way (free)
  __shared__ u16 Bl[128*40];
  const int t = threadIdx.x;
  const int w = t>>6, lane = t&63, hi = lane>>4, lo = lane&15;
  const int row0 = blockIdx.x*128;
  const int col0 = blockIdx.y*128;
  const int z = blockIdx.z;
  const float* W    = (z==0)?Wq:(z==1)?Wk:Wv;
  const float* bias = (z==0)?bq:(z==1)?bk:bv;
  const int srow = t>>2, scol = t&3;

  f32x4 acc[4][4];
#pragma unroll
  for (int i=0;i<4;i++)
#pragma unroll
    for (int j=0;j<4;j++) acc[i][j] = (f32x4)0.0f;

  const u16* Ab = &Al[((w>>1)*64 + lo)*40 + hi*8];
  const u16* Bb = &Bl[((w&1)*64 + lo)*40 + hi*8];

  for (int kt=0; kt<NHID; kt+=32){
#pragma unroll
    for (int it=0; it<2; it++){
      const int r = it*64 + srow;
      const float* ga = x + (size_t)(row0+r)*NHID + kt + scol*8;
      float4 a0 = *(const float4*)ga;
      float4 a1 = *(const float4*)(ga+4);
      float ta[8] = {a0.x,a0.y,a0.z,a0.w,a1.x,a1.y,a1.z,a1.w};
      *(bf16x8*)&Al[r*40 + scol*8] = pack8(ta);
      const float* gb = W + (size_t)(col0+r)*NHID + kt + scol*8;
      float4 b0 = *(const float4*)gb;
      float4 b1 = *(const float4*)(gb+4);
      float tb[8] = {b0.x,b0.y,b0.z,b0.w,b1.x,b1.y,b1.z,b1.w};
      *(bf16x8*)&Bl[r*40 + scol*8] = pack8(tb);
    }
    __syncthreads();
    bf16x8 af[4], bg[4];
#pragma unroll
    for (int i=0;i<4;i++){
      af[i] = *(const bf16x8*)(Ab + i*16*40);
      bg[i] = *(const bf16x8*)(Bb + i*16*40);
    }
#pragma unroll
    for (int i=0;i<4;i++)
#pragma unroll
      for (int j=0;j<4;j++)
        acc[i][j] = mfma16(af[i], bg[j], acc[i][j]);
    __syncthreads();
  }

  const int mbase = row0 + (w>>1)*64;
  const int nbase = col0 + (w&1)*64;
  u16* dstT = (z==1)? kTb : vTb;
#pragma unroll
  for (int i=0;i<4;i++){
#pragma unroll
    for (int r=0;r<4;r++){
      const int m = mbase + i*16 + hi*4 + r;   // D row = (lane>>4)*4+reg  [m89]
      const int b = m/NS, s = m%NS;
      const float mv = mask[b*NS + s];
#pragma unroll
      for (int j=0;j<4;j++){
        const int n = nbase + j*16 + lo;       // D col = lane&15
        float v = acc[i][j][r] + bias[n];
        const int hh = n>>6, d = n&63;
        if (z==0){
          qb[((size_t)(b*NHEAD + hh)*NS + s)*NDK + d] = f2b(v);
        } else {
          dstT[((size_t)(b*NHEAD + hh)*NDK + d)*NS + s] = f2b(v*mv);
        }
      }
    }
  }
}

// ---------------- 2) S->K projection, per (b,h) ------------------------------
// MODE 0: kproj[kk][d] = sum_s Wf[kk][s]*k[s][d] + bf   (stored [kk][d])
// MODE 1: vproj[kk][d] = sum_s We[kk][s]*v[s][d] + be   (stored TRANSPOSED [d][kk])
template<int MODE>
__global__ __launch_bounds__(256) void proj_kernel(
    const u16* __restrict__ XT,   // [BH][64][200] bf16 (kT or vT)
    const float* __restrict__ Wp, // [64][200] fp32
    const float* __restrict__ bias,
    u16* __restrict__ outb)       // [BH][64][64] bf16
{
  __shared__ u16 WL[64*232];      // ld=232: K padded 200->224, zeros; 2-way free
  __shared__ u16 XL[64*232];
  const int t=threadIdx.x, w=t>>6, lane=t&63, hi=lane>>4, lo=lane&15;
  const int bh = blockIdx.x;
  { const int row=t>>2, c=t&3;    // zero pad cols 200..231
    *(bf16x8*)&WL[row*232 + 200 + c*8] = (bf16x8)0;
    *(bf16x8*)&XL[row*232 + 200 + c*8] = (bf16x8)0;
  }
  for (int c0=t; c0<1600; c0+=256){
    const int row = c0/25, col8 = (c0%25)*8;
    const float* g = Wp + row*200 + col8;
    float4 u0=*(const float4*)g, u1=*(const float4*)(g+4);
    float tw[8]={u0.x,u0.y,u0.z,u0.w,u1.x,u1.y,u1.z,u1.w};
    *(bf16x8*)&WL[row*232+col8] = pack8(tw);
    *(bf16x8*)&XL[row*232+col8] = *(const bf16x8*)(XT + (size_t)bh*12800 + c0*8);
  }
  __syncthreads();
  const int m0=(w>>1)*32, n0=(w&1)*32;
  f32x4 acc[2][2];
#pragma unroll
  for(int i=0;i<2;i++)
#pragma unroll
    for(int j=0;j<2;j++) acc[i][j]=(f32x4)0.0f;
  const u16* Ab=&WL[(m0+lo)*232 + hi*8];
  const u16* Bb=&XL[(n0+lo)*232 + hi*8];
#pragma unroll
  for (int kt=0; kt<224; kt+=32){
    bf16x8 a0=*(const bf16x8*)(Ab+kt),      a1=*(const bf16x8*)(Ab+16*232+kt);
    bf16x8 b0=*(const bf16x8*)(Bb+kt),      b1=*(const bf16x8*)(Bb+16*232+kt);
    acc[0][0]=mfma16(a0,b0,acc[0][0]);
    acc[0][1]=mfma16(a0,b1,acc[0][1]);
    acc[1][0]=mfma16(a1,b0,acc[1][0]);
    acc[1][1]=mfma16(a1,b1,acc[1][1]);
  }
#pragma unroll
  for(int i=0;i<2;i++)
#pragma unroll
    for(int r=0;r<4;r++){
      const int kk = m0 + i*16 + hi*4 + r;
      const float bv_ = bias[kk];
#pragma unroll
      for(int j=0;j<2;j++){
        const int d = n0 + j*16 + lo;
        const float v = acc[i][j][r] + bv_;
        if (MODE==0) outb[(size_t)bh*4096 + (size_t)kk*64 + d] = f2b(v);
        else         outb[(size_t)bh*4096 + (size_t)d*64 + kk] = f2b(v);
      }
    }
}

// ---------------- 3) fused attention per (b,h) -------------------------------
// scores = q @ kproj^T / 8 ; softmax over kk ; p -> d_out ; ctx = p @ vproj
__global__ __launch_bounds__(256) void attn_kernel(
    const u16* __restrict__ qb,     // [BH][200][64]
    const u16* __restrict__ kproj,  // [BH][64][64]  ([kk][d])
    const u16* __restrict__ vprojT, // [BH][64][64]  ([d][kk])
    float* __restrict__ pout,       // [BH][200][64] fp32
    u16* __restrict__ ctxb)         // [B][200][768] bf16
{
  __shared__ u16 QL[208*72];   // q tile (rows 200..207 zero); reused as P after barrier
  __shared__ u16 KP[64*72];
  __shared__ u16 VP[64*72];
  const int t=threadIdx.x, w=t>>6, lane=t&63, hi=lane>>4, lo=lane&15;
  const int bh = blockIdx.x;
  for (int c=t;c<1600;c+=256){
    const int row=c>>3, col8=(c&7)*8;
    *(bf16x8*)&QL[row*72+col8] = *(const bf16x8*)(qb + (size_t)bh*12800 + c*8);
  }
  if (t<72){ const int row=200+t/9, col8=(t%9)*8; *(bf16x8*)&QL[row*72+col8]=(bf16x8)0; }
  for (int c=t;c<512;c+=256){
    const int row=c>>3, col8=(c&7)*8;
    *(bf16x8*)&KP[row*72+col8] = *(const bf16x8*)(kproj  + (size_t)bh*4096 + c*8);
    *(bf16x8*)&VP[row*72+col8] = *(const bf16x8*)(vprojT + (size_t)bh*4096 + c*8);
  }
  __syncthreads();
  // M=208 rows split over 4 waves: 4/3/3/3 m-frags
  const int mf0 = (w==0)?0:(1+w*3);
  const int nmf = (w==0)?4:3;
  f32x4 acc[4][4];
#pragma unroll
  for(int i=0;i<4;i++)
#pragma unroll
    for(int j=0;j<4;j++) acc[i][j]=(f32x4)0.0f;
#pragma unroll
  for (int ks=0; ks<2; ks++){
    bf16x8 a[4], bb[4];
#pragma unroll
    for (int j=0;j<4;j++) bb[j]=*(const bf16x8*)&KP[(j*16+lo)*72 + ks*32 + hi*8];
#pragma unroll
    for (int i=0;i<4;i++) if (i<nmf) a[i]=*(const bf16x8*)&QL[((mf0+i)*16+lo)*72 + ks*32 + hi*8];
#pragma unroll
    for (int i=0;i<4;i++) if (i<nmf)
#pragma unroll
      for (int j=0;j<4;j++)
        acc[i][j]=mfma16(a[i],bb[j],acc[i][j]);
  }
  __syncthreads();   // all waves done reading QL as q -> reuse as P storage

  const int b=bh/NHEAD, hh=bh%NHEAD;
#pragma unroll
  for (int i=0;i<4;i++) if (i<nmf){
#pragma unroll
    for (int r=0;r<4;r++){
      const int q = (mf0+i)*16 + hi*4 + r;
      float s0=acc[i][0][r]*0.125f, s1=acc[i][1][r]*0.125f,
            s2=acc[i][2][r]*0.125f, s3=acc[i][3][r]*0.125f;
      float mx=fmaxf(fmaxf(s0,s1),fmaxf(s2,s3));
      mx=fmaxf(mx,__shfl_xor(mx,1)); mx=fmaxf(mx,__shfl_xor(mx,2));
      mx=fmaxf(mx,__shfl_xor(mx,4)); mx=fmaxf(mx,__shfl_xor(mx,8));
      float e0=__expf(s0-mx), e1=__expf(s1-mx), e2=__expf(s2-mx), e3=__expf(s3-mx);
      float sm=e0+e1+e2+e3;
      sm+=__shfl_xor(sm,1); sm+=__shfl_xor(sm,2); sm+=__shfl_xor(sm,4); sm+=__shfl_xor(sm,8);
      const float inv=1.0f/sm;
      const float p0=e0*inv,p1=e1*inv,p2=e2*inv,p3=e3*inv;
      if (q<NS){
        float* pg = pout + ((size_t)bh*NS + q)*NK + lo;
        pg[0]=p0; pg[16]=p1; pg[32]=p2; pg[48]=p3;
      }
      u16* pl = &QL[q*72 + lo];
      pl[0]=f2b(p0); pl[16]=f2b(p1); pl[32]=f2b(p2); pl[48]=f2b(p3);
    }
  }
  // ctx = P @ vproj  (A=P [q][kk] from QL, B=vprojT [d][kk]); waves read only own rows
  f32x4 acc2[4][4];
#pragma unroll
  for(int i=0;i<4;i++)
#pragma unroll
    for(int j=0;j<4;j++) acc2[i][j]=(f32x4)0.0f;
#pragma unroll
  for (int ks=0; ks<2; ks++){
    bf16x8 a[4], bb[4];
#pragma unroll
    for (int j=0;j<4;j++) bb[j]=*(const bf16x8*)&VP[(j*16+lo)*72 + ks*32 + hi*8];
#pragma unroll
    for (int i=0;i<4;i++) if (i<nmf) a[i]=*(const bf16x8*)&QL[((mf0+i)*16+lo)*72 + ks*32 + hi*8];
#pragma unroll
    for (int i=0;i<4;i++) if (i<nmf)
#pragma unroll
      for (int j=0;j<4;j++)
        acc2[i][j]=mfma16(a[i],bb[j],acc2[i][j]);
  }
#pragma unroll
  for (int i=0;i<4;i++) if (i<nmf)
#pragma unroll
    for (int r=0;r<4;r++){
      const int q=(mf0+i)*16+hi*4+r;
      if (q<NS){
#pragma unroll
        for (int j=0;j<4;j++){
          const int d=j*16+lo;
          ctxb[((size_t)b*NS+q)*NHID + hh*NDK + d] = f2b(acc2[i][j][r]);
        }
      }
    }
}

// ---------------- 4) output projection + bias + residual ---------------------
__global__ __launch_bounds__(256) void dproj_kernel(
    const u16* __restrict__ ctxb, const float* __restrict__ Wd,
    const float* __restrict__ bd, const float* __restrict__ x,
    float* __restrict__ out)
{
  __shared__ u16 Al[128*40];
  __shared__ u16 Bl[128*40];
  const int t=threadIdx.x, w=t>>6, lane=t&63, hi=lane>>4, lo=lane&15;
  const int row0=blockIdx.x*128, col0=blockIdx.y*128;
  const int srow=t>>2, scol=t&3;
  f32x4 acc[4][4];
#pragma unroll
  for (int i=0;i<4;i++)
#pragma unroll
    for (int j=0;j<4;j++) acc[i][j]=(f32x4)0.0f;
  const u16* Ab=&Al[((w>>1)*64+lo)*40 + hi*8];
  const u16* Bb=&Bl[((w&1)*64+lo)*40 + hi*8];

  for (int kt=0; kt<NHID; kt+=32){
#pragma unroll
    for (int it=0; it<2; it++){
      const int r=it*64+srow;
      *(bf16x8*)&Al[r*40+scol*8] = *(const bf16x8*)(ctxb + (size_t)(row0+r)*NHID + kt + scol*8);
      const float* gb = Wd + (size_t)(col0+r)*NHID + kt + scol*8;
      float4 b0=*(const float4*)gb, b1=*(const float4*)(gb+4);
      float tb[8]={b0.x,b0.y,b0.z,b0.w,b1.x,b1.y,b1.z,b1.w};
      *(bf16x8*)&Bl[r*40+scol*8]=pack8(tb);
    }
    __syncthreads();
    bf16x8 af[4], bg[4];
#pragma unroll
    for (int i=0;i<4;i++){
      af[i] = *(const bf16x8*)(Ab + i*16*40);
      bg[i] = *(const bf16x8*)(Bb + i*16*40);
    }
#pragma unroll
    for (int i=0;i<4;i++)
#pragma unroll
      for (int j=0;j<4;j++)
        acc[i][j] = mfma16(af[i], bg[j], acc[i][j]);
    __syncthreads();
  }
  const int mbase=row0+(w>>1)*64, nbase=col0+(w&1)*64;
#pragma unroll
  for (int i=0;i<4;i++)
#pragma unroll
    for (int r=0;r<4;r++){
      const int m=mbase+i*16+hi*4+r;
#pragma unroll
      for (int j=0;j<4;j++){
        const int n=nbase+j*16+lo;
        out[(size_t)m*NHID+n] = acc[i][j][r] + bd[n] + x[(size_t)m*NHID+n];
      }
    }
}

// ---------------- 5) in-place LayerNorm over H=768 ---------------------------
__global__ __launch_bounds__(192) void ln_kernel(
    float* __restrict__ out, const float* __restrict__ gamma, const float* __restrict__ beta)
{
  __shared__ float ps[3], pq[3];
  const int t = threadIdx.x;
  float4* row = (float4*)(out + (size_t)blockIdx.x*NHID);
  float4 v = row[t];
  float s = v.x+v.y+v.z+v.w;
  float q = v.x*v.x + v.y*v.y + v.z*v.z + v.w*v.w;
#pragma unroll
  for (int m=1;m<64;m<<=1){ s += __shfl_xor(s,m); q += __shfl_xor(q,m); }
  if ((t&63)==0){ ps[t>>6]=s; pq[t>>6]=q; }
  __syncthreads();
  s = ps[0]+ps[1]+ps[2]; q = pq[0]+pq[1]+pq[2];
  const float mu = s*(1.0f/768.0f);
  const float var = q*(1.0f/768.0f) - mu*mu;
  const float rs = rsqrtf(var + 1e-12f);
  const float4 g  = ((const float4*)gamma)[t];
  const float4 be = ((const float4*)beta)[t];
  float4 o;
  o.x=(v.x-mu)*rs*g.x+be.x; o.y=(v.y-mu)*rs*g.y+be.y;
  o.z=(v.z-mu)*rs*g.z+be.z; o.w=(v.w-mu)*rs*g.w+be.w;
  row[t]=o;
}

// -----------------------------------------------------------------------------
extern "C" void kernel_launch(void* const* d_in, const int* in_sizes, int n_in,
                              void* d_out, int out_size, void* d_ws, size_t ws_size,
                              hipStream_t stream)
{
  (void)in_sizes; (void)n_in; (void)out_size; (void)ws_size;
  const float* x    = (const float*)d_in[0];
  const float* mask = (const float*)d_in[1];
  const float* Wq   = (const float*)d_in[2];
  const float* bq   = (const float*)d_in[3];
  const float* Wk   = (const float*)d_in[4];
  const float* bk   = (const float*)d_in[5];
  const float* Wv   = (const float*)d_in[6];
  const float* bv   = (const float*)d_in[7];
  const float* We   = (const float*)d_in[8];
  const float* be   = (const float*)d_in[9];
  const float* Wf   = (const float*)d_in[10];
  const float* bf   = (const float*)d_in[11];
  const float* Wd   = (const float*)d_in[12];
  const float* bd   = (const float*)d_in[13];
  const float* gamma= (const float*)d_in[14];
  const float* beta = (const float*)d_in[15];

  float* out  = (float*)d_out;                    // [51200][768] fp32
  float* pout = out + (size_t)NM*NHID;            // [3072][200][64] fp32

  // ws layout (bf16 buffers), peak 261,095,424 B via overlays:
  //   [0, 78.6M)      q
  //   [78.6M,157.3M)  kT   -> reused for vprojT after proj<0>
  //   [157.3M,235.9M) vT   -> reused for ctx after proj<1>
  //   [235.9M,261.1M) kproj
  char* ws = (char*)d_ws;
  u16* qb     = (u16*)(ws);
  u16* kTb    = (u16*)(ws + 78643200ull);
  u16* vTb    = (u16*)(ws + 157286400ull);
  u16* kproj  = (u16*)(ws + 235929600ull);
  u16* vprojT = (u16*)(ws + 78643200ull);   // overlays kT (dead after proj<0>)
  u16* ctxb   = (u16*)(ws + 157286400ull);  // overlays vT (dead after proj<1>)

  qkv_kernel<<<dim3(400,6,3),256,0,stream>>>(x,Wq,bq,Wk,bk,Wv,bv,mask,qb,kTb,vTb);
  proj_kernel<0><<<NBH,256,0,stream>>>(kTb, Wf, bf, kproj);
  proj_kernel<1><<<NBH,256,0,stream>>>(vTb, We, be, vprojT);
  attn_kernel<<<NBH,256,0,stream>>>(qb, kproj, vprojT, pout, ctxb);
  dproj_kernel<<<dim3(400,6),256,0,stream>>>(ctxb, Wd, bd, x, out);
  ln_kernel<<<NM,192,0,stream>>>(out, gamma, beta);
}

// Round 2
// 625.395 us; speedup vs baseline: 1.7711x; 1.7711x over previous
//
#include <hip/hip_runtime.h>
#include <stdint.h>

typedef unsigned short u16;
typedef short bf16x8 __attribute__((ext_vector_type(8)));
typedef float f32x4 __attribute__((ext_vector_type(4)));

#define NB   256
#define NS   200
#define NHID 768
#define NHEAD 12
#define NDK  64
#define NK   64
#define NBH  (NB*NHEAD)   // 3072
#define NM   (NB*NS)      // 51200
#define SP   224          // padded S for xbT / Wfe

__device__ __forceinline__ u16 f2b(float f){
  unsigned u = __builtin_bit_cast(unsigned, f);
  return (u16)((u + 0x7FFFu + ((u>>16)&1u)) >> 16);   // RNE, finite inputs
}
__device__ __forceinline__ f32x4 mfma16(bf16x8 a, bf16x8 b, f32x4 c){
  return __builtin_amdgcn_mfma_f32_16x16x32_bf16(a, b, c, 0, 0, 0);
}
__device__ __forceinline__ void gload16(u16* l, const u16* g){
  __builtin_amdgcn_global_load_lds(
      (const __attribute__((address_space(1))) void*)g,
      (__attribute__((address_space(3))) void*)l, 16, 0, 0);
}

// ---------------- K0a: pack Wq/Wk/Wv/Wd fp32 -> bf16 -------------------------
__global__ __launch_bounds__(256) void pack_w(
    const float* __restrict__ Wq, const float* __restrict__ Wk,
    const float* __restrict__ Wv, const float* __restrict__ Wd,
    u16* __restrict__ Wqb, u16* __restrict__ Wkb,
    u16* __restrict__ Wvb, u16* __restrict__ Wdb)
{
  const int i = blockIdx.x*256 + threadIdx.x;   // grid 2304 -> 589824 exact
  Wqb[i]=f2b(Wq[i]); Wkb[i]=f2b(Wk[i]); Wvb[i]=f2b(Wv[i]); Wdb[i]=f2b(Wd[i]);
}

// ---------------- K0b: pack Wf(0..63)/We(64..127) -> [128][224] bf16, 0-pad --
__global__ __launch_bounds__(256) void pack_wfe(
    const float* __restrict__ Wf, const float* __restrict__ We, u16* __restrict__ Wfeb)
{
  const int r = blockIdx.x, s = threadIdx.x;
  if (s < SP){
    float v = 0.f;
    if (s < NS) v = (r<64) ? Wf[r*NS+s] : We[(r-64)*NS+s];
    Wfeb[r*SP+s] = f2b(v);
  }
}

// ---------------- K0c: rowsums[b][kk] = sum_s W_{f,e}[kk][s]*mask[b][s] ------
__global__ __launch_bounds__(128) void rowsums_k(
    const float* __restrict__ Wf, const float* __restrict__ We,
    const float* __restrict__ mask, float* __restrict__ rs)
{
  const int b = blockIdx.x, kk = threadIdx.x;
  const float* src = (kk<64) ? (Wf + kk*NS) : (We + (kk-64)*NS);
  float acc = 0.f;
  for (int s=0;s<NS;s++) acc += src[s]*mask[b*NS+s];
  rs[b*128+kk] = acc;
}

// ---------------- K1: x -> xb (bf16) and xbT (bf16, masked, [b][768][224]) ---
__global__ __launch_bounds__(256) void transpose_x(
    const float* __restrict__ x, const float* __restrict__ mask,
    u16* __restrict__ xb, u16* __restrict__ xbT)
{
  __shared__ u16 LT[64*232];
  const int t = threadIdx.x, b = blockIdx.x, n0 = blockIdx.y*64;
  for (int i=0;i<50;i++){
    const int idx = i*256 + t;
    const int s = idx>>6, n = idx&63;
    const size_t gi = ((size_t)b*NS + s)*NHID + n0 + n;
    const float v = x[gi];
    xb[gi] = f2b(v);
    const float mv = mask[b*NS+s];
    LT[n*232 + s] = f2b(v*mv);
  }
  __syncthreads();
  const int row = t>>2, cb = t&3;
  u16* dst = xbT + (size_t)b*NHID*SP + (size_t)(n0+row)*SP;
  for (int i=0;i<7;i++){
    const int c = cb + i*4;                 // 28 chunks of 8
    bf16x8 vv = (c<25) ? *(const bf16x8*)&LT[row*232 + c*8] : (bf16x8)0;
    *(bf16x8*)&dst[c*8] = vv;
  }
}

// ---------------- K3: yfe[b][128][768] = Wfe @ xbT[b]^T ----------------------
// A = Wfeb [128][224] (shared), B = xbT[b] [768][224]; contraction over s.
__global__ __launch_bounds__(256) void gemm_yfe(
    const u16* __restrict__ Wfeb, const u16* __restrict__ xbT, u16* __restrict__ yfe)
{
  __shared__ u16 Al[128*64];
  __shared__ u16 Bl[128*64];
  const int t=threadIdx.x, w=t>>6, lane=t&63, hi=lane>>4, lo=lane&15;
  const int sr=lane>>3, sc=lane&7;
  const int b=blockIdx.x, col0=blockIdx.y*128;
  const u16* Bg = xbT + (size_t)b*NHID*SP;
  f32x4 acc[4][4];
#pragma unroll
  for(int i=0;i<4;i++)
#pragma unroll
    for(int j=0;j<4;j++) acc[i][j]=(f32x4)0.0f;
  const u16* Ab=&Al[((w>>1)*64+lo)*64 + hi*8];
  const u16* Bb=&Bl[((w&1)*64+lo)*64 + hi*8];

  for (int kt=0; kt<192; kt+=64){
#pragma unroll
    for (int i8=0;i8<4;i8++){
      const int r = w*32 + i8*8 + sr;
      gload16(&Al[r*64 + sc*8], Wfeb + (size_t)r*SP + kt + sc*8);
      gload16(&Bl[r*64 + sc*8], Bg + (size_t)(col0+r)*SP + kt + sc*8);
    }
    asm volatile("s_waitcnt vmcnt(0)" ::: "memory");
    __syncthreads();
#pragma unroll
    for (int ks=0; ks<2; ks++){
      bf16x8 a[4], bfr[4];
#pragma unroll
      for (int i=0;i<4;i++) a[i]   = *(const bf16x8*)(Ab + i*16*64 + ks*32);
#pragma unroll
      for (int j=0;j<4;j++) bfr[j] = *(const bf16x8*)(Bb + j*16*64 + ks*32);
#pragma unroll
      for (int i=0;i<4;i++)
#pragma unroll
        for (int j=0;j<4;j++) acc[i][j] = mfma16(a[i], bfr[j], acc[i][j]);
    }
    __syncthreads();
  }
  // tail: kt=192, BK=32 (cols 200..223 of Wfe are zero -> garbage in xbT killed)
#pragma unroll
  for (int i8=0;i8<2;i8++){
    const int r2 = w*32 + i8*16 + (lane>>2);
    gload16(&Al[r2*32 + (lane&3)*8], Wfeb + (size_t)r2*SP + 192 + (lane&3)*8);
    gload16(&Bl[r2*32 + (lane&3)*8], Bg + (size_t)(col0+r2)*SP + 192 + (lane&3)*8);
  }
  asm volatile("s_waitcnt vmcnt(0)" ::: "memory");
  __syncthreads();
  {
    bf16x8 a[4], bfr[4];
#pragma unroll
    for (int i=0;i<4;i++) a[i]   = *(const bf16x8*)&Al[((w>>1)*64+i*16+lo)*32 + hi*8];
#pragma unroll
    for (int j=0;j<4;j++) bfr[j] = *(const bf16x8*)&Bl[((w&1)*64+j*16+lo)*32 + hi*8];
#pragma unroll
    for (int i=0;i<4;i++)
#pragma unroll
      for (int j=0;j<4;j++) acc[i][j] = mfma16(a[i], bfr[j], acc[i][j]);
  }
  const int mbase=(w>>1)*64, nbase=col0+(w&1)*64;
#pragma unroll
  for (int i=0;i<4;i++)
#pragma unroll
    for (int r=0;r<4;r++){
      const int m = mbase + i*16 + hi*4 + r;
#pragma unroll
      for (int j=0;j<4;j++){
        const int n = nbase + j*16 + lo;
        yfe[(size_t)b*98304 + (size_t)m*NHID + n] = f2b(acc[i][j][r]);
      }
    }
}

// ---------------- K2: qb[bh][s][d] = xb @ Wq^T + bq --------------------------
__global__ __launch_bounds__(256) void gemm_q(
    const u16* __restrict__ xb, const u16* __restrict__ Wqb,
    const float* __restrict__ bq, u16* __restrict__ qb)
{
  __shared__ u16 Al[128*64];
  __shared__ u16 Bl[128*64];
  const int t=threadIdx.x, w=t>>6, lane=t&63, hi=lane>>4, lo=lane&15;
  const int sr=lane>>3, sc=lane&7;
  const int row0=blockIdx.x*128, col0=blockIdx.y*128;
  f32x4 acc[4][4];
#pragma unroll
  for(int i=0;i<4;i++)
#pragma unroll
    for(int j=0;j<4;j++) acc[i][j]=(f32x4)0.0f;
  const u16* Ab=&Al[((w>>1)*64+lo)*64 + hi*8];
  const u16* Bb=&Bl[((w&1)*64+lo)*64 + hi*8];

  for (int kt=0; kt<NHID; kt+=64){
#pragma unroll
    for (int i8=0;i8<4;i8++){
      const int r = w*32 + i8*8 + sr;
      gload16(&Al[r*64 + sc*8], xb  + (size_t)(row0+r)*NHID + kt + sc*8);
      gload16(&Bl[r*64 + sc*8], Wqb + (size_t)(col0+r)*NHID + kt + sc*8);
    }
    asm volatile("s_waitcnt vmcnt(0)" ::: "memory");
    __syncthreads();
#pragma unroll
    for (int ks=0; ks<2; ks++){
      bf16x8 a[4], bfr[4];
#pragma unroll
      for (int i=0;i<4;i++) a[i]   = *(const bf16x8*)(Ab + i*16*64 + ks*32);
#pragma unroll
      for (int j=0;j<4;j++) bfr[j] = *(const bf16x8*)(Bb + j*16*64 + ks*32);
#pragma unroll
      for (int i=0;i<4;i++)
#pragma unroll
        for (int j=0;j<4;j++) acc[i][j] = mfma16(a[i], bfr[j], acc[i][j]);
    }
    __syncthreads();
  }
  const int mbase=row0+(w>>1)*64, nbase=col0+(w&1)*64;
#pragma unroll
  for (int i=0;i<4;i++)
#pragma unroll
    for (int r=0;r<4;r++){
      const int m = mbase + i*16 + hi*4 + r;
      const int b = m/NS, s = m%NS;
      u16* qrow = qb + (size_t)b*153600 + (size_t)s*64;
#pragma unroll
      for (int j=0;j<4;j++){
        const int n = nbase + j*16 + lo;
        qrow[(n>>6)*12800 + (n&63)] = f2b(acc[i][j][r] + bq[n]);
      }
    }
}

// ---------------- K4a: kproj[b][64][768] = yf @ Wk^T + rsf*bk + bf -----------
__global__ __launch_bounds__(256) void gemm_kproj(
    const u16* __restrict__ yfe, const u16* __restrict__ Wkb,
    const float* __restrict__ rs, const float* __restrict__ bk,
    const float* __restrict__ bff, u16* __restrict__ kproj)
{
  __shared__ u16 Al[64*64];
  __shared__ u16 Bl[128*64];
  const int t=threadIdx.x, w=t>>6, lane=t&63, hi=lane>>4, lo=lane&15;
  const int sr=lane>>3, sc=lane&7;
  const int b=blockIdx.x, col0=blockIdx.y*128;
  const u16* yf = yfe + (size_t)b*98304;
  f32x4 acc[2][4];
#pragma unroll
  for(int i=0;i<2;i++)
#pragma unroll
    for(int j=0;j<4;j++) acc[i][j]=(f32x4)0.0f;
  const u16* Ab=&Al[((w>>1)*32+lo)*64 + hi*8];
  const u16* Bb=&Bl[((w&1)*64+lo)*64 + hi*8];

  for (int kt=0; kt<NHID; kt+=64){
#pragma unroll
    for (int i8=0;i8<2;i8++){
      const int r = w*16 + i8*8 + sr;
      gload16(&Al[r*64 + sc*8], yf + (size_t)r*NHID + kt + sc*8);
    }
#pragma unroll
    for (int i8=0;i8<4;i8++){
      const int r = w*32 + i8*8 + sr;
      gload16(&Bl[r*64 + sc*8], Wkb + (size_t)(col0+r)*NHID + kt + sc*8);
    }
    asm volatile("s_waitcnt vmcnt(0)" ::: "memory");
    __syncthreads();
#pragma unroll
    for (int ks=0; ks<2; ks++){
      bf16x8 a[2], bfr[4];
#pragma unroll
      for (int i=0;i<2;i++) a[i]   = *(const bf16x8*)(Ab + i*16*64 + ks*32);
#pragma unroll
      for (int j=0;j<4;j++) bfr[j] = *(const bf16x8*)(Bb + j*16*64 + ks*32);
#pragma unroll
      for (int i=0;i<2;i++)
#pragma unroll
        for (int j=0;j<4;j++) acc[i][j] = mfma16(a[i], bfr[j], acc[i][j]);
    }
    __syncthreads();
  }
  const int mbase=(w>>1)*32, nbase=col0+(w&1)*64;
#pragma unroll
  for (int i=0;i<2;i++)
#pragma unroll
    for (int r=0;r<4;r++){
      const int m = mbase + i*16 + hi*4 + r;          // kk
      const float rsv = rs[b*128 + m], bfv = bff[m];
#pragma unroll
      for (int j=0;j<4;j++){
        const int n = nbase + j*16 + lo;              // hd
        kproj[(size_t)b*49152 + (size_t)m*NHID + n] = f2b(acc[i][j][r] + rsv*bk[n] + bfv);
      }
    }
}

// ---------------- K4b: vprojT[b][768][64] = Wv @ ye^T + bv*rse + be ----------
// writes into the dead yf half of yfe's region (per-b first 49152 elems)
__global__ __launch_bounds__(256) void gemm_vprojT(
    const u16* yfe, const u16* __restrict__ Wvb,
    const float* __restrict__ rs, const float* __restrict__ bv,
    const float* __restrict__ bee, u16* vout)
{
  __shared__ u16 Al[128*64];
  __shared__ u16 Bl[64*64];
  const int t=threadIdx.x, w=t>>6, lane=t&63, hi=lane>>4, lo=lane&15;
  const int sr=lane>>3, sc=lane&7;
  const int b=blockIdx.x, row0=blockIdx.y*128;
  const u16* ye = yfe + (size_t)b*98304 + 49152;
  f32x4 acc[4][2];
#pragma unroll
  for(int i=0;i<4;i++)
#pragma unroll
    for(int j=0;j<2;j++) acc[i][j]=(f32x4)0.0f;
  const u16* Ab=&Al[((w>>1)*64+lo)*64 + hi*8];
  const u16* Bb=&Bl[((w&1)*32+lo)*64 + hi*8];

  for (int kt=0; kt<NHID; kt+=64){
#pragma unroll
    for (int i8=0;i8<4;i8++){
      const int r = w*32 + i8*8 + sr;
      gload16(&Al[r*64 + sc*8], Wvb + (size_t)(row0+r)*NHID + kt + sc*8);
    }
#pragma unroll
    for (int i8=0;i8<2;i8++){
      const int r = w*16 + i8*8 + sr;
      gload16(&Bl[r*64 + sc*8], ye + (size_t)r*NHID + kt + sc*8);
    }
    asm volatile("s_waitcnt vmcnt(0)" ::: "memory");
    __syncthreads();
#pragma unroll
    for (int ks=0; ks<2; ks++){
      bf16x8 a[4], bfr[2];
#pragma unroll
      for (int i=0;i<4;i++) a[i]   = *(const bf16x8*)(Ab + i*16*64 + ks*32);
#pragma unroll
      for (int j=0;j<2;j++) bfr[j] = *(const bf16x8*)(Bb + j*16*64 + ks*32);
#pragma unroll
      for (int i=0;i<4;i++)
#pragma unroll
        for (int j=0;j<2;j++) acc[i][j] = mfma16(a[i], bfr[j], acc[i][j]);
    }
    __syncthreads();
  }
  const int mbase=row0+(w>>1)*64, nbase=(w&1)*32;
#pragma unroll
  for (int i=0;i<4;i++)
#pragma unroll
    for (int r=0;r<4;r++){
      const int m = mbase + i*16 + hi*4 + r;          // hd
      const float bvv = bv[m];
#pragma unroll
      for (int j=0;j<2;j++){
        const int n = nbase + j*16 + lo;              // kk
        vout[(size_t)b*98304 + (size_t)m*64 + n] = f2b(acc[i][j][r] + rs[b*128+64+n]*bvv + bee[n]);
      }
    }
}

// ---------------- K5: fused attention per (b,h) ------------------------------
__global__ __launch_bounds__(256) void attn_kernel(
    const u16* __restrict__ qb,      // [BH][200][64]
    const u16* __restrict__ kproj,   // [B][64][768]  ([kk][h*64+d])
    const u16* __restrict__ vprojT,  // [B][768][64]  ([h*64+d][kk])
    float* __restrict__ pout,        // [BH][200][64] fp32
    u16* __restrict__ ctxb)          // [B][200][768] bf16
{
  __shared__ u16 QL[208*72];   // q tile (rows 200..207 zero); reused as P
  __shared__ u16 KP[64*72];
  __shared__ u16 VP[64*72];
  const int t=threadIdx.x, w=t>>6, lane=t&63, hi=lane>>4, lo=lane&15;
  const int bh = blockIdx.x, b=bh/NHEAD, hh=bh%NHEAD;
  for (int c=t;c<1600;c+=256){
    const int row=c>>3, col8=(c&7)*8;
    *(bf16x8*)&QL[row*72+col8] = *(const bf16x8*)(qb + (size_t)bh*12800 + c*8);
  }
  if (t<72){ const int row=200+t/9, col8=(t%9)*8; *(bf16x8*)&QL[row*72+col8]=(bf16x8)0; }
  for (int c=t;c<512;c+=256){
    const int row=c>>3, col8=(c&7)*8;
    *(bf16x8*)&KP[row*72+col8] = *(const bf16x8*)(kproj  + (size_t)b*49152 + (size_t)row*NHID + hh*64 + col8);
    *(bf16x8*)&VP[row*72+col8] = *(const bf16x8*)(vprojT + (size_t)b*98304 + (size_t)(hh*64+row)*64 + col8);
  }
  __syncthreads();
  const int mf0 = (w==0)?0:(1+w*3);
  const int nmf = (w==0)?4:3;
  f32x4 acc[4][4];
#pragma unroll
  for(int i=0;i<4;i++)
#pragma unroll
    for(int j=0;j<4;j++) acc[i][j]=(f32x4)0.0f;
#pragma unroll
  for (int ks=0; ks<2; ks++){
    bf16x8 a[4], bb[4];
#pragma unroll
    for (int j=0;j<4;j++) bb[j]=*(const bf16x8*)&KP[(j*16+lo)*72 + ks*32 + hi*8];
#pragma unroll
    for (int i=0;i<4;i++) if (i<nmf) a[i]=*(const bf16x8*)&QL[((mf0+i)*16+lo)*72 + ks*32 + hi*8];
#pragma unroll
    for (int i=0;i<4;i++) if (i<nmf)
#pragma unroll
      for (int j=0;j<4;j++)
        acc[i][j]=mfma16(a[i],bb[j],acc[i][j]);
  }
  __syncthreads();

#pragma unroll
  for (int i=0;i<4;i++) if (i<nmf){
#pragma unroll
    for (int r=0;r<4;r++){
      const int q = (mf0+i)*16 + hi*4 + r;
      float s0=acc[i][0][r]*0.125f, s1=acc[i][1][r]*0.125f,
            s2=acc[i][2][r]*0.125f, s3=acc[i][3][r]*0.125f;
      float mx=fmaxf(fmaxf(s0,s1),fmaxf(s2,s3));
      mx=fmaxf(mx,__shfl_xor(mx,1)); mx=fmaxf(mx,__shfl_xor(mx,2));
      mx=fmaxf(mx,__shfl_xor(mx,4)); mx=fmaxf(mx,__shfl_xor(mx,8));
      float e0=__expf(s0-mx), e1=__expf(s1-mx), e2=__expf(s2-mx), e3=__expf(s3-mx);
      float sm=e0+e1+e2+e3;
      sm+=__shfl_xor(sm,1); sm+=__shfl_xor(sm,2); sm+=__shfl_xor(sm,4); sm+=__shfl_xor(sm,8);
      const float inv=1.0f/sm;
      const float p0=e0*inv,p1=e1*inv,p2=e2*inv,p3=e3*inv;
      if (q<NS){
        float* pg = pout + ((size_t)bh*NS + q)*NK + lo;
        pg[0]=p0; pg[16]=p1; pg[32]=p2; pg[48]=p3;
      }
      u16* pl = &QL[q*72 + lo];
      pl[0]=f2b(p0); pl[16]=f2b(p1); pl[32]=f2b(p2); pl[48]=f2b(p3);
    }
  }
  f32x4 acc2[4][4];
#pragma unroll
  for(int i=0;i<4;i++)
#pragma unroll
    for(int j=0;j<4;j++) acc2[i][j]=(f32x4)0.0f;
#pragma unroll
  for (int ks=0; ks<2; ks++){
    bf16x8 a[4], bb[4];
#pragma unroll
    for (int j=0;j<4;j++) bb[j]=*(const bf16x8*)&VP[(j*16+lo)*72 + ks*32 + hi*8];
#pragma unroll
    for (int i=0;i<4;i++) if (i<nmf) a[i]=*(const bf16x8*)&QL[((mf0+i)*16+lo)*72 + ks*32 + hi*8];
#pragma unroll
    for (int i=0;i<4;i++) if (i<nmf)
#pragma unroll
      for (int j=0;j<4;j++)
        acc2[i][j]=mfma16(a[i],bb[j],acc2[i][j]);
  }
#pragma unroll
  for (int i=0;i<4;i++) if (i<nmf)
#pragma unroll
    for (int r=0;r<4;r++){
      const int q=(mf0+i)*16+hi*4+r;
      if (q<NS){
#pragma unroll
        for (int j=0;j<4;j++){
          const int d=j*16+lo;
          ctxb[((size_t)b*NS+q)*NHID + hh*NDK + d] = f2b(acc2[i][j][r]);
        }
      }
    }
}

// ---------------- K6: out = ctx @ Wd^T + bd + x ------------------------------
__global__ __launch_bounds__(256) void gemm_out(
    const u16* __restrict__ ctxb, const u16* __restrict__ Wdb,
    const float* __restrict__ bd, const float* __restrict__ x,
    float* __restrict__ outp)
{
  __shared__ u16 Al[128*64];
  __shared__ u16 Bl[128*64];
  const int t=threadIdx.x, w=t>>6, lane=t&63, hi=lane>>4, lo=lane&15;
  const int sr=lane>>3, sc=lane&7;
  const int row0=blockIdx.x*128, col0=blockIdx.y*128;
  f32x4 acc[4][4];
#pragma unroll
  for(int i=0;i<4;i++)
#pragma unroll
    for(int j=0;j<4;j++) acc[i][j]=(f32x4)0.0f;
  const u16* Ab=&Al[((w>>1)*64+lo)*64 + hi*8];
  const u16* Bb=&Bl[((w&1)*64+lo)*64 + hi*8];

  for (int kt=0; kt<NHID; kt+=64){
#pragma unroll
    for (int i8=0;i8<4;i8++){
      const int r = w*32 + i8*8 + sr;
      gload16(&Al[r*64 + sc*8], ctxb + (size_t)(row0+r)*NHID + kt + sc*8);
      gload16(&Bl[r*64 + sc*8], Wdb  + (size_t)(col0+r)*NHID + kt + sc*8);
    }
    asm volatile("s_waitcnt vmcnt(0)" ::: "memory");
    __syncthreads();
#pragma unroll
    for (int ks=0; ks<2; ks++){
      bf16x8 a[4], bfr[4];
#pragma unroll
      for (int i=0;i<4;i++) a[i]   = *(const bf16x8*)(Ab + i*16*64 + ks*32);
#pragma unroll
      for (int j=0;j<4;j++) bfr[j] = *(const bf16x8*)(Bb + j*16*64 + ks*32);
#pragma unroll
      for (int i=0;i<4;i++)
#pragma unroll
        for (int j=0;j<4;j++) acc[i][j] = mfma16(a[i], bfr[j], acc[i][j]);
    }
    __syncthreads();
  }
  const int mbase=row0+(w>>1)*64, nbase=col0+(w&1)*64;
#pragma unroll
  for (int i=0;i<4;i++)
#pragma unroll
    for (int r=0;r<4;r++){
      const int m = mbase + i*16 + hi*4 + r;
#pragma unroll
      for (int j=0;j<4;j++){
        const int n = nbase + j*16 + lo;
        outp[(size_t)m*NHID+n] = acc[i][j][r] + bd[n] + x[(size_t)m*NHID+n];
      }
    }
}

// ---------------- K7: in-place LayerNorm over H=768 --------------------------
__global__ __launch_bounds__(192) void ln_kernel(
    float* __restrict__ out, const float* __restrict__ gamma, const float* __restrict__ beta)
{
  __shared__ float ps[3], pq[3];
  const int t = threadIdx.x;
  float4* row = (float4*)(out + (size_t)blockIdx.x*NHID);
  float4 v = row[t];
  float s = v.x+v.y+v.z+v.w;
  float q = v.x*v.x + v.y*v.y + v.z*v.z + v.w*v.w;
#pragma unroll
  for (int m=1;m<64;m<<=1){ s += __shfl_xor(s,m); q += __shfl_xor(q,m); }
  if ((t&63)==0){ ps[t>>6]=s; pq[t>>6]=q; }
  __syncthreads();
  s = ps[0]+ps[1]+ps[2]; q = pq[0]+pq[1]+pq[2];
  const float mu = s*(1.0f/768.0f);
  const float var = q*(1.0f/768.0f) - mu*mu;
  const float rs = rsqrtf(var + 1e-12f);
  const float4 g  = ((const float4*)gamma)[t];
  const float4 be = ((const float4*)beta)[t];
  float4 o;
  o.x=(v.x-mu)*rs*g.x+be.x; o.y=(v.y-mu)*rs*g.y+be.y;
  o.z=(v.z-mu)*rs*g.z+be.z; o.w=(v.w-mu)*rs*g.w+be.w;
  row[t]=o;
}

// -----------------------------------------------------------------------------
extern "C" void kernel_launch(void* const* d_in, const int* in_sizes, int n_in,
                              void* d_out, int out_size, void* d_ws, size_t ws_size,
                              hipStream_t stream)
{
  (void)in_sizes; (void)n_in; (void)out_size; (void)ws_size;
  const float* x    = (const float*)d_in[0];
  const float* mask = (const float*)d_in[1];
  const float* Wq   = (const float*)d_in[2];
  const float* bq   = (const float*)d_in[3];
  const float* Wk   = (const float*)d_in[4];
  const float* bk   = (const float*)d_in[5];
  const float* Wv   = (const float*)d_in[6];
  const float* bv   = (const float*)d_in[7];
  const float* We   = (const float*)d_in[8];
  const float* be   = (const float*)d_in[9];
  const float* Wf   = (const float*)d_in[10];
  const float* bf   = (const float*)d_in[11];
  const float* Wd   = (const float*)d_in[12];
  const float* bd   = (const float*)d_in[13];
  const float* gamma= (const float*)d_in[14];
  const float* beta = (const float*)d_in[15];

  float* out  = (float*)d_out;                    // [51200][768] fp32
  float* pout = out + (size_t)NM*NHID;            // [3072][200][64] fp32

  // ws layout (bytes), peak ~247.1 MB:
  //  A @0          : xb [51200][768] bf16 (78,643,200)      -> ctx (same size)
  //  B @78,643,200 : xbT [256][768][224] bf16 (88,080,384)  -> qb (78,643,200)
  //  C @166,723,584: yfe [256][128][768] bf16 (50,331,648); vprojT overlays yf half
  //  D @217,055,232: kproj [256][64][768] bf16 (25,165,824)
  //  W @242,221,056: Wqb,Wkb,Wvb,Wdb (4x1,179,648), Wfeb (57,344), rowsums fp32 (131,072)
  char* ws = (char*)d_ws;
  u16* xb    = (u16*)(ws);
  u16* ctxb  = (u16*)(ws);                        // overlays xb (dead after gemm_q)
  u16* xbT   = (u16*)(ws + 78643200ull);
  u16* qb    = (u16*)(ws + 78643200ull);          // overlays xbT (dead after gemm_yfe)
  u16* yfe   = (u16*)(ws + 166723584ull);
  u16* vprojT= (u16*)(ws + 166723584ull);         // overlays yf half per-b
  u16* kproj = (u16*)(ws + 217055232ull);
  u16* Wqb   = (u16*)(ws + 242221056ull);
  u16* Wkb   = (u16*)(ws + 243400704ull);
  u16* Wvb   = (u16*)(ws + 244580352ull);
  u16* Wdb   = (u16*)(ws + 245760000ull);
  u16* Wfeb  = (u16*)(ws + 246939648ull);
  float* rsb = (float*)(ws + 246996992ull);

  pack_w  <<<2304,256,0,stream>>>(Wq,Wk,Wv,Wd,Wqb,Wkb,Wvb,Wdb);
  pack_wfe<<<128, 256,0,stream>>>(Wf,We,Wfeb);
  rowsums_k<<<NB, 128,0,stream>>>(Wf,We,mask,rsb);
  transpose_x<<<dim3(NB,12),256,0,stream>>>(x,mask,xb,xbT);
  gemm_yfe<<<dim3(NB,6),256,0,stream>>>(Wfeb,xbT,yfe);      // uses xbT, then dead
  gemm_q  <<<dim3(400,6),256,0,stream>>>(xb,Wqb,bq,qb);     // qb overlays xbT
  gemm_kproj <<<dim3(NB,6),256,0,stream>>>(yfe,Wkb,rsb,bk,bf,kproj);
  gemm_vprojT<<<dim3(NB,6),256,0,stream>>>(yfe,Wvb,rsb,bv,be,vprojT);
  attn_kernel<<<NBH,256,0,stream>>>(qb,kproj,vprojT,pout,ctxb);
  gemm_out<<<dim3(400,6),256,0,stream>>>(ctxb,Wdb,bd,x,out);
  ln_kernel<<<NM,192,0,stream>>>(out,gamma,beta);
}

// Round 3
// 588.462 us; speedup vs baseline: 1.8822x; 1.0628x over previous
//
#include <hip/hip_runtime.h>
#include <stdint.h>

typedef unsigned short u16;
typedef short bf16x8 __attribute__((ext_vector_type(8)));
typedef float f32x4 __attribute__((ext_vector_type(4)));

#define NB   256
#define NS   200
#define NHID 768
#define NHEAD 12
#define NDK  64
#define NK   64
#define NBH  (NB*NHEAD)   // 3072
#define NM   (NB*NS)      // 51200
#define SP   224          // padded S for xbT / Wfe

__device__ __forceinline__ u16 f2b(float f){
  unsigned u = __builtin_bit_cast(unsigned, f);
  return (u16)((u + 0x7FFFu + ((u>>16)&1u)) >> 16);   // RNE, finite inputs
}
__device__ __forceinline__ bf16x8 pack8(const float* v){
  bf16x8 r;
#pragma unroll
  for (int i=0;i<8;i++) r[i] = (short)f2b(v[i]);
  return r;
}
__device__ __forceinline__ f32x4 mfma16(bf16x8 a, bf16x8 b, f32x4 c){
  return __builtin_amdgcn_mfma_f32_16x16x32_bf16(a, b, c, 0, 0, 0);
}
__device__ __forceinline__ void gload16(u16* l, const u16* g){
  __builtin_amdgcn_global_load_lds(
      (const __attribute__((address_space(1))) void*)g,
      (__attribute__((address_space(3))) void*)l, 16, 0, 0);
}

// ---------------- K0a: pack Wq/Wk/Wv/Wd fp32 -> bf16 -------------------------
__global__ __launch_bounds__(256) void pack_w(
    const float* __restrict__ Wq, const float* __restrict__ Wk,
    const float* __restrict__ Wv, const float* __restrict__ Wd,
    u16* __restrict__ Wqb, u16* __restrict__ Wkb,
    u16* __restrict__ Wvb, u16* __restrict__ Wdb)
{
  const int i = blockIdx.x*256 + threadIdx.x;   // grid 2304 -> 589824 exact
  Wqb[i]=f2b(Wq[i]); Wkb[i]=f2b(Wk[i]); Wvb[i]=f2b(Wv[i]); Wdb[i]=f2b(Wd[i]);
}

// ---------------- K0b: pack Wf(0..63)/We(64..127) -> [128][224] bf16, 0-pad --
__global__ __launch_bounds__(256) void pack_wfe(
    const float* __restrict__ Wf, const float* __restrict__ We, u16* __restrict__ Wfeb)
{
  const int r = blockIdx.x, s = threadIdx.x;
  if (s < SP){
    float v = 0.f;
    if (s < NS) v = (r<64) ? Wf[r*NS+s] : We[(r-64)*NS+s];
    Wfeb[r*SP+s] = f2b(v);
  }
}

// ---------------- K0c: rowsums[b][kk] = sum_s W_{f,e}[kk][s]*mask[b][s] ------
__global__ __launch_bounds__(128) void rowsums_k(
    const float* __restrict__ Wf, const float* __restrict__ We,
    const float* __restrict__ mask, float* __restrict__ rs)
{
  const int b = blockIdx.x, kk = threadIdx.x;
  const float* src = (kk<64) ? (Wf + kk*NS) : (We + (kk-64)*NS);
  float acc = 0.f;
  for (int s=0;s<NS;s++) acc += src[s]*mask[b*NS+s];
  rs[b*128+kk] = acc;
}

// ---------------- K1: x -> xb (bf16) and xbT (bf16, masked, [b][768][224]) ---
__global__ __launch_bounds__(256) void transpose_x(
    const float* __restrict__ x, const float* __restrict__ mask,
    u16* __restrict__ xb, u16* __restrict__ xbT)
{
  __shared__ u16 LT[64*232];
  const int t = threadIdx.x, b = blockIdx.x, n0 = blockIdx.y*64;
  for (int i=0;i<50;i++){
    const int idx = i*256 + t;
    const int s = idx>>6, n = idx&63;
    const size_t gi = ((size_t)b*NS + s)*NHID + n0 + n;
    const float v = x[gi];
    xb[gi] = f2b(v);
    const float mv = mask[b*NS+s];
    LT[n*232 + s] = f2b(v*mv);
  }
  __syncthreads();
  const int row = t>>2, cb = t&3;
  u16* dst = xbT + (size_t)b*NHID*SP + (size_t)(n0+row)*SP;
  for (int i=0;i<7;i++){
    const int c = cb + i*4;                 // 28 chunks of 8
    bf16x8 vv = (c<25) ? *(const bf16x8*)&LT[row*232 + c*8] : (bf16x8)0;
    *(bf16x8*)&dst[c*8] = vv;
  }
}

// ---------------- K3: yfe[b][128][768] = Wfe @ xbT[b]^T ----------------------
__global__ __launch_bounds__(256) void gemm_yfe(
    const u16* __restrict__ Wfeb, const u16* __restrict__ xbT, u16* __restrict__ yfe)
{
  __shared__ u16 Al[128*64];
  __shared__ u16 Bl[128*64];
  const int t=threadIdx.x, w=t>>6, lane=t&63, hi=lane>>4, lo=lane&15;
  const int sr=lane>>3, sc=lane&7;
  const int b=blockIdx.x, col0=blockIdx.y*128;
  const u16* Bg = xbT + (size_t)b*NHID*SP;
  f32x4 acc[4][4];
#pragma unroll
  for(int i=0;i<4;i++)
#pragma unroll
    for(int j=0;j<4;j++) acc[i][j]=(f32x4)0.0f;
  const u16* Ab=&Al[((w>>1)*64+lo)*64 + hi*8];
  const u16* Bb=&Bl[((w&1)*64+lo)*64 + hi*8];

  for (int kt=0; kt<192; kt+=64){
#pragma unroll
    for (int i8=0;i8<4;i8++){
      const int r = w*32 + i8*8 + sr;
      gload16(&Al[r*64 + sc*8], Wfeb + (size_t)r*SP + kt + sc*8);
      gload16(&Bl[r*64 + sc*8], Bg + (size_t)(col0+r)*SP + kt + sc*8);
    }
    asm volatile("s_waitcnt vmcnt(0)" ::: "memory");
    __syncthreads();
#pragma unroll
    for (int ks=0; ks<2; ks++){
      bf16x8 a[4], bfr[4];
#pragma unroll
      for (int i=0;i<4;i++) a[i]   = *(const bf16x8*)(Ab + i*16*64 + ks*32);
#pragma unroll
      for (int j=0;j<4;j++) bfr[j] = *(const bf16x8*)(Bb + j*16*64 + ks*32);
#pragma unroll
      for (int i=0;i<4;i++)
#pragma unroll
        for (int j=0;j<4;j++) acc[i][j] = mfma16(a[i], bfr[j], acc[i][j]);
    }
    __syncthreads();
  }
  // tail: kt=192, BK=32 (cols 200..223 of Wfe are zero -> garbage in xbT killed)
#pragma unroll
  for (int i8=0;i8<2;i8++){
    const int r2 = w*32 + i8*16 + (lane>>2);
    gload16(&Al[r2*32 + (lane&3)*8], Wfeb + (size_t)r2*SP + 192 + (lane&3)*8);
    gload16(&Bl[r2*32 + (lane&3)*8], Bg + (size_t)(col0+r2)*SP + 192 + (lane&3)*8);
  }
  asm volatile("s_waitcnt vmcnt(0)" ::: "memory");
  __syncthreads();
  {
    bf16x8 a[4], bfr[4];
#pragma unroll
    for (int i=0;i<4;i++) a[i]   = *(const bf16x8*)&Al[((w>>1)*64+i*16+lo)*32 + hi*8];
#pragma unroll
    for (int j=0;j<4;j++) bfr[j] = *(const bf16x8*)&Bl[((w&1)*64+j*16+lo)*32 + hi*8];
#pragma unroll
    for (int i=0;i<4;i++)
#pragma unroll
      for (int j=0;j<4;j++) acc[i][j] = mfma16(a[i], bfr[j], acc[i][j]);
  }
  const int mbase=(w>>1)*64, nbase=col0+(w&1)*64;
#pragma unroll
  for (int i=0;i<4;i++)
#pragma unroll
    for (int r=0;r<4;r++){
      const int m = mbase + i*16 + hi*4 + r;
#pragma unroll
      for (int j=0;j<4;j++){
        const int n = nbase + j*16 + lo;
        yfe[(size_t)b*98304 + (size_t)m*NHID + n] = f2b(acc[i][j][r]);
      }
    }
}

// ---------------- ring GEMM: C = A @ B^T (+bias, +resid), M=51200, N=768 -----
// BM=256, BN=256, BK=32, 4-slot LDS ring, 512 thr, 8 waves (2M x 4N).
// Paired-row LDS layout: elem (row r, k c8-chunk) at [r>>1][ ((r&1)*4+c8) ^ ((r>>1)&7) ]
// (XOR swizzle applied on global SOURCE at stage and on ds_read addr; LDS dest linear.)
// Counted vmcnt: stage tile t+3 issued before compute(t); wait vmcnt(8) per iter.
template<int EPI>   // 0: store qb bf16 scattered; 1: out fp32 + bias + resid
__global__ __launch_bounds__(512, 2) void gemm_ring(
    const u16* __restrict__ Ag_, const u16* __restrict__ Bg_,
    const float* __restrict__ bias, const float* __restrict__ resid,
    void* __restrict__ Cout)
{
  __shared__ u16 AS[4][8192];
  __shared__ u16 BS[4][8192];
  const int t = threadIdx.x;
  const int w = t>>6, lane = t&63, hi = lane>>4, lo = lane&15;
  const int wm = w>>2, wn = w&3;
  const int row0 = blockIdx.x*256, col0 = blockIdx.y*256;
  const u16* Ag = Ag_ + (size_t)row0*NHID;
  const u16* Bg = Bg_ + (size_t)col0*NHID;
  const int rp0 = t>>3, cc = t&7;

  f32x4 acc[8][4];
#pragma unroll
  for (int i=0;i<8;i++)
#pragma unroll
    for (int j=0;j<4;j++) acc[i][j] = (f32x4)0.0f;

  int aoff[8], boff[4];
#pragma unroll
  for (int i=0;i<8;i++){
    const int r = wm*128 + i*16 + lo;
    const int rp = r>>1, c = (r&1)*4 + hi;
    aoff[i] = rp*64 + ((c ^ (rp&7))<<3);
  }
#pragma unroll
  for (int j=0;j<4;j++){
    const int n = wn*64 + j*16 + lo;
    const int rp = n>>1, c = (n&1)*4 + hi;
    boff[j] = rp*64 + ((c ^ (rp&7))<<3);
  }

  auto stage = [&](int s, int kt){
#pragma unroll
    for (int i8=0;i8<2;i8++){
      const int rp = i8*64 + rp0;
      const int c  = cc ^ (rp&7);
      const int grow = rp*2 + (c>>2);
      const int gcol = (c&3)<<3;
      gload16(&AS[s][rp*64 + cc*8], Ag + (size_t)grow*NHID + kt + gcol);
      gload16(&BS[s][rp*64 + cc*8], Bg + (size_t)grow*NHID + kt + gcol);
    }
  };
  auto body = [&](const u16* as_, const u16* bs_){
    bf16x8 av[8], bvv[4];
#pragma unroll
    for (int j=0;j<4;j++) bvv[j] = *(const bf16x8*)(bs_ + boff[j]);
#pragma unroll
    for (int i=0;i<8;i++) av[i] = *(const bf16x8*)(as_ + aoff[i]);
    __builtin_amdgcn_s_setprio(1);
#pragma unroll
    for (int i=0;i<8;i++)
#pragma unroll
      for (int j=0;j<4;j++) acc[i][j] = mfma16(av[i], bvv[j], acc[i][j]);
    __builtin_amdgcn_s_setprio(0);
  };
  auto step = [&](int tt, int s){
    if (tt+3 < 24) stage((s+3)&3, (tt+3)*32);
    body(AS[s], BS[s]);
    if (tt <= 20)      { asm volatile("s_waitcnt vmcnt(8)" ::: "memory"); }
    else if (tt == 21) { asm volatile("s_waitcnt vmcnt(4)" ::: "memory"); }
    else if (tt == 22) { asm volatile("s_waitcnt vmcnt(0)" ::: "memory"); }
    if (tt < 23){
      __builtin_amdgcn_sched_barrier(0);
      asm volatile("s_barrier" ::: "memory");
      __builtin_amdgcn_sched_barrier(0);
    }
  };

  stage(0,0); stage(1,32); stage(2,64);
  asm volatile("s_waitcnt vmcnt(8)" ::: "memory");
  asm volatile("s_barrier" ::: "memory");
  __builtin_amdgcn_sched_barrier(0);

#pragma unroll
  for (int tt=0; tt<24; tt+=4){
    step(tt,0); step(tt+1,1); step(tt+2,2); step(tt+3,3);
  }

#pragma unroll
  for (int i=0;i<8;i++)
#pragma unroll
    for (int q=0;q<4;q++){
      const int m = row0 + wm*128 + i*16 + hi*4 + q;
#pragma unroll
      for (int j=0;j<4;j++){
        const int n = col0 + wn*64 + j*16 + lo;
        const float v = acc[i][j][q] + bias[n];
        if constexpr (EPI==0){
          const int b = m/NS, s = m - b*NS;
          ((u16*)Cout)[(((size_t)b*NHEAD + (n>>6))*NS + s)*NDK + (n&63)] = f2b(v);
        } else {
          const size_t gi = (size_t)m*NHID + n;
          ((float*)Cout)[gi] = v + resid[gi];
        }
      }
    }
}

// ---------------- K4a: kproj[b][64][768] = yf @ Wk^T + rsf*bk + bf -----------
__global__ __launch_bounds__(256) void gemm_kproj(
    const u16* __restrict__ yfe, const u16* __restrict__ Wkb,
    const float* __restrict__ rs, const float* __restrict__ bk,
    const float* __restrict__ bff, u16* __restrict__ kproj)
{
  __shared__ u16 Al[64*64];
  __shared__ u16 Bl[128*64];
  const int t=threadIdx.x, w=t>>6, lane=t&63, hi=lane>>4, lo=lane&15;
  const int sr=lane>>3, sc=lane&7;
  const int b=blockIdx.x, col0=blockIdx.y*128;
  const u16* yf = yfe + (size_t)b*98304;
  f32x4 acc[2][4];
#pragma unroll
  for(int i=0;i<2;i++)
#pragma unroll
    for(int j=0;j<4;j++) acc[i][j]=(f32x4)0.0f;
  const u16* Ab=&Al[((w>>1)*32+lo)*64 + hi*8];
  const u16* Bb=&Bl[((w&1)*64+lo)*64 + hi*8];

  for (int kt=0; kt<NHID; kt+=64){
#pragma unroll
    for (int i8=0;i8<2;i8++){
      const int r = w*16 + i8*8 + sr;
      gload16(&Al[r*64 + sc*8], yf + (size_t)r*NHID + kt + sc*8);
    }
#pragma unroll
    for (int i8=0;i8<4;i8++){
      const int r = w*32 + i8*8 + sr;
      gload16(&Bl[r*64 + sc*8], Wkb + (size_t)(col0+r)*NHID + kt + sc*8);
    }
    asm volatile("s_waitcnt vmcnt(0)" ::: "memory");
    __syncthreads();
#pragma unroll
    for (int ks=0; ks<2; ks++){
      bf16x8 a[2], bfr[4];
#pragma unroll
      for (int i=0;i<2;i++) a[i]   = *(const bf16x8*)(Ab + i*16*64 + ks*32);
#pragma unroll
      for (int j=0;j<4;j++) bfr[j] = *(const bf16x8*)(Bb + j*16*64 + ks*32);
#pragma unroll
      for (int i=0;i<2;i++)
#pragma unroll
        for (int j=0;j<4;j++) acc[i][j] = mfma16(a[i], bfr[j], acc[i][j]);
    }
    __syncthreads();
  }
  const int mbase=(w>>1)*32, nbase=col0+(w&1)*64;
#pragma unroll
  for (int i=0;i<2;i++)
#pragma unroll
    for (int r=0;r<4;r++){
      const int m = mbase + i*16 + hi*4 + r;          // kk
      const float rsv = rs[b*128 + m], bfv = bff[m];
#pragma unroll
      for (int j=0;j<4;j++){
        const int n = nbase + j*16 + lo;              // hd
        kproj[(size_t)b*49152 + (size_t)m*NHID + n] = f2b(acc[i][j][r] + rsv*bk[n] + bfv);
      }
    }
}

// ---------------- K4b: vprojT[b][768][64] = Wv @ ye^T + bv*rse + be ----------
__global__ __launch_bounds__(256) void gemm_vprojT(
    const u16* yfe, const u16* __restrict__ Wvb,
    const float* __restrict__ rs, const float* __restrict__ bv,
    const float* __restrict__ bee, u16* vout)
{
  __shared__ u16 Al[128*64];
  __shared__ u16 Bl[64*64];
  const int t=threadIdx.x, w=t>>6, lane=t&63, hi=lane>>4, lo=lane&15;
  const int sr=lane>>3, sc=lane&7;
  const int b=blockIdx.x, row0=blockIdx.y*128;
  const u16* ye = yfe + (size_t)b*98304 + 49152;
  f32x4 acc[4][2];
#pragma unroll
  for(int i=0;i<4;i++)
#pragma unroll
    for(int j=0;j<2;j++) acc[i][j]=(f32x4)0.0f;
  const u16* Ab=&Al[((w>>1)*64+lo)*64 + hi*8];
  const u16* Bb=&Bl[((w&1)*32+lo)*64 + hi*8];

  for (int kt=0; kt<NHID; kt+=64){
#pragma unroll
    for (int i8=0;i8<4;i8++){
      const int r = w*32 + i8*8 + sr;
      gload16(&Al[r*64 + sc*8], Wvb + (size_t)(row0+r)*NHID + kt + sc*8);
    }
#pragma unroll
    for (int i8=0;i8<2;i8++){
      const int r = w*16 + i8*8 + sr;
      gload16(&Bl[r*64 + sc*8], ye + (size_t)r*NHID + kt + sc*8);
    }
    asm volatile("s_waitcnt vmcnt(0)" ::: "memory");
    __syncthreads();
#pragma unroll
    for (int ks=0; ks<2; ks++){
      bf16x8 a[4], bfr[2];
#pragma unroll
      for (int i=0;i<4;i++) a[i]   = *(const bf16x8*)(Ab + i*16*64 + ks*32);
#pragma unroll
      for (int j=0;j<2;j++) bfr[j] = *(const bf16x8*)(Bb + j*16*64 + ks*32);
#pragma unroll
      for (int i=0;i<4;i++)
#pragma unroll
        for (int j=0;j<2;j++) acc[i][j] = mfma16(a[i], bfr[j], acc[i][j]);
    }
    __syncthreads();
  }
  const int mbase=row0+(w>>1)*64, nbase=(w&1)*32;
#pragma unroll
  for (int i=0;i<4;i++)
#pragma unroll
    for (int r=0;r<4;r++){
      const int m = mbase + i*16 + hi*4 + r;          // hd
      const float bvv = bv[m];
#pragma unroll
      for (int j=0;j<2;j++){
        const int n = nbase + j*16 + lo;              // kk
        vout[(size_t)b*98304 + (size_t)m*64 + n] = f2b(acc[i][j][r] + rs[b*128+64+n]*bvv + bee[n]);
      }
    }
}

// ---------------- K5: fused attention per (b,h) ------------------------------
__global__ __launch_bounds__(256) void attn_kernel(
    const u16* __restrict__ qb,      // [BH][200][64]
    const u16* __restrict__ kproj,   // [B][64][768]  ([kk][h*64+d])
    const u16* __restrict__ vprojT,  // [B][768][64]  ([h*64+d][kk])
    float* __restrict__ pout,        // [BH][200][64] fp32
    u16* __restrict__ ctxb)          // [B][200][768] bf16
{
  __shared__ u16 QL[208*72];   // q tile (rows 200..207 zero); reused as P
  __shared__ u16 KP[64*72];
  __shared__ u16 VP[64*72];
  const int t=threadIdx.x, w=t>>6, lane=t&63, hi=lane>>4, lo=lane&15;
  const int bh = blockIdx.x, b=bh/NHEAD, hh=bh%NHEAD;
  for (int c=t;c<1600;c+=256){
    const int row=c>>3, col8=(c&7)*8;
    *(bf16x8*)&QL[row*72+col8] = *(const bf16x8*)(qb + (size_t)bh*12800 + c*8);
  }
  if (t<72){ const int row=200+t/9, col8=(t%9)*8; *(bf16x8*)&QL[row*72+col8]=(bf16x8)0; }
  for (int c=t;c<512;c+=256){
    const int row=c>>3, col8=(c&7)*8;
    *(bf16x8*)&KP[row*72+col8] = *(const bf16x8*)(kproj  + (size_t)b*49152 + (size_t)row*NHID + hh*64 + col8);
    *(bf16x8*)&VP[row*72+col8] = *(const bf16x8*)(vprojT + (size_t)b*98304 + (size_t)(hh*64+row)*64 + col8);
  }
  __syncthreads();
  const int mf0 = (w==0)?0:(1+w*3);
  const int nmf = (w==0)?4:3;
  f32x4 acc[4][4];
#pragma unroll
  for(int i=0;i<4;i++)
#pragma unroll
    for(int j=0;j<4;j++) acc[i][j]=(f32x4)0.0f;
#pragma unroll
  for (int ks=0; ks<2; ks++){
    bf16x8 a[4], bb[4];
#pragma unroll
    for (int j=0;j<4;j++) bb[j]=*(const bf16x8*)&KP[(j*16+lo)*72 + ks*32 + hi*8];
#pragma unroll
    for (int i=0;i<4;i++) if (i<nmf) a[i]=*(const bf16x8*)&QL[((mf0+i)*16+lo)*72 + ks*32 + hi*8];
#pragma unroll
    for (int i=0;i<4;i++) if (i<nmf)
#pragma unroll
      for (int j=0;j<4;j++)
        acc[i][j]=mfma16(a[i],bb[j],acc[i][j]);
  }
  __syncthreads();

#pragma unroll
  for (int i=0;i<4;i++) if (i<nmf){
#pragma unroll
    for (int r=0;r<4;r++){
      const int q = (mf0+i)*16 + hi*4 + r;
      float s0=acc[i][0][r]*0.125f, s1=acc[i][1][r]*0.125f,
            s2=acc[i][2][r]*0.125f, s3=acc[i][3][r]*0.125f;
      float mx=fmaxf(fmaxf(s0,s1),fmaxf(s2,s3));
      mx=fmaxf(mx,__shfl_xor(mx,1)); mx=fmaxf(mx,__shfl_xor(mx,2));
      mx=fmaxf(mx,__shfl_xor(mx,4)); mx=fmaxf(mx,__shfl_xor(mx,8));
      float e0=__expf(s0-mx), e1=__expf(s1-mx), e2=__expf(s2-mx), e3=__expf(s3-mx);
      float sm=e0+e1+e2+e3;
      sm+=__shfl_xor(sm,1); sm+=__shfl_xor(sm,2); sm+=__shfl_xor(sm,4); sm+=__shfl_xor(sm,8);
      const float inv=1.0f/sm;
      const float p0=e0*inv,p1=e1*inv,p2=e2*inv,p3=e3*inv;
      if (q<NS){
        float* pg = pout + ((size_t)bh*NS + q)*NK + lo;
        pg[0]=p0; pg[16]=p1; pg[32]=p2; pg[48]=p3;
      }
      u16* pl = &QL[q*72 + lo];
      pl[0]=f2b(p0); pl[16]=f2b(p1); pl[32]=f2b(p2); pl[48]=f2b(p3);
    }
  }
  f32x4 acc2[4][4];
#pragma unroll
  for(int i=0;i<4;i++)
#pragma unroll
    for(int j=0;j<4;j++) acc2[i][j]=(f32x4)0.0f;
#pragma unroll
  for (int ks=0; ks<2; ks++){
    bf16x8 a[4], bb[4];
#pragma unroll
    for (int j=0;j<4;j++) bb[j]=*(const bf16x8*)&VP[(j*16+lo)*72 + ks*32 + hi*8];
#pragma unroll
    for (int i=0;i<4;i++) if (i<nmf) a[i]=*(const bf16x8*)&QL[((mf0+i)*16+lo)*72 + ks*32 + hi*8];
#pragma unroll
    for (int i=0;i<4;i++) if (i<nmf)
#pragma unroll
      for (int j=0;j<4;j++)
        acc2[i][j]=mfma16(a[i],bb[j],acc2[i][j]);
  }
#pragma unroll
  for (int i=0;i<4;i++) if (i<nmf)
#pragma unroll
    for (int r=0;r<4;r++){
      const int q=(mf0+i)*16+hi*4+r;
      if (q<NS){
#pragma unroll
        for (int j=0;j<4;j++){
          const int d=j*16+lo;
          ctxb[((size_t)b*NS+q)*NHID + hh*NDK + d] = f2b(acc2[i][j][r]);
        }
      }
    }
}

// ---------------- K7: in-place LayerNorm over H=768 --------------------------
__global__ __launch_bounds__(192) void ln_kernel(
    float* __restrict__ out, const float* __restrict__ gamma, const float* __restrict__ beta)
{
  __shared__ float ps[3], pq[3];
  const int t = threadIdx.x;
  float4* row = (float4*)(out + (size_t)blockIdx.x*NHID);
  float4 v = row[t];
  float s = v.x+v.y+v.z+v.w;
  float q = v.x*v.x + v.y*v.y + v.z*v.z + v.w*v.w;
#pragma unroll
  for (int m=1;m<64;m<<=1){ s += __shfl_xor(s,m); q += __shfl_xor(q,m); }
  if ((t&63)==0){ ps[t>>6]=s; pq[t>>6]=q; }
  __syncthreads();
  s = ps[0]+ps[1]+ps[2]; q = pq[0]+pq[1]+pq[2];
  const float mu = s*(1.0f/768.0f);
  const float var = q*(1.0f/768.0f) - mu*mu;
  const float rs = rsqrtf(var + 1e-12f);
  const float4 g  = ((const float4*)gamma)[t];
  const float4 be = ((const float4*)beta)[t];
  float4 o;
  o.x=(v.x-mu)*rs*g.x+be.x; o.y=(v.y-mu)*rs*g.y+be.y;
  o.z=(v.z-mu)*rs*g.z+be.z; o.w=(v.w-mu)*rs*g.w+be.w;
  row[t]=o;
}

// -----------------------------------------------------------------------------
extern "C" void kernel_launch(void* const* d_in, const int* in_sizes, int n_in,
                              void* d_out, int out_size, void* d_ws, size_t ws_size,
                              hipStream_t stream)
{
  (void)in_sizes; (void)n_in; (void)out_size; (void)ws_size;
  const float* x    = (const float*)d_in[0];
  const float* mask = (const float*)d_in[1];
  const float* Wq   = (const float*)d_in[2];
  const float* bq   = (const float*)d_in[3];
  const float* Wk   = (const float*)d_in[4];
  const float* bk   = (const float*)d_in[5];
  const float* Wv   = (const float*)d_in[6];
  const float* bv   = (const float*)d_in[7];
  const float* We   = (const float*)d_in[8];
  const float* be   = (const float*)d_in[9];
  const float* Wf   = (const float*)d_in[10];
  const float* bf   = (const float*)d_in[11];
  const float* Wd   = (const float*)d_in[12];
  const float* bd   = (const float*)d_in[13];
  const float* gamma= (const float*)d_in[14];
  const float* beta = (const float*)d_in[15];

  float* out  = (float*)d_out;                    // [51200][768] fp32
  float* pout = out + (size_t)NM*NHID;            // [3072][200][64] fp32

  char* ws = (char*)d_ws;
  u16* xb    = (u16*)(ws);
  u16* ctxb  = (u16*)(ws);                        // overlays xb (dead after gemm_ring<0>)
  u16* xbT   = (u16*)(ws + 78643200ull);
  u16* qb    = (u16*)(ws + 78643200ull);          // overlays xbT (dead after gemm_yfe)
  u16* yfe   = (u16*)(ws + 166723584ull);
  u16* vprojT= (u16*)(ws + 166723584ull);         // overlays yf half per-b
  u16* kproj = (u16*)(ws + 217055232ull);
  u16* Wqb   = (u16*)(ws + 242221056ull);
  u16* Wkb   = (u16*)(ws + 243400704ull);
  u16* Wvb   = (u16*)(ws + 244580352ull);
  u16* Wdb   = (u16*)(ws + 245760000ull);
  u16* Wfeb  = (u16*)(ws + 246939648ull);
  float* rsb = (float*)(ws + 246996992ull);

  pack_w  <<<2304,256,0,stream>>>(Wq,Wk,Wv,Wd,Wqb,Wkb,Wvb,Wdb);
  pack_wfe<<<128, 256,0,stream>>>(Wf,We,Wfeb);
  rowsums_k<<<NB, 128,0,stream>>>(Wf,We,mask,rsb);
  transpose_x<<<dim3(NB,12),256,0,stream>>>(x,mask,xb,xbT);
  gemm_yfe<<<dim3(NB,6),256,0,stream>>>(Wfeb,xbT,yfe);      // uses xbT, then dead
  gemm_ring<0><<<dim3(200,3),512,0,stream>>>(xb,Wqb,bq,nullptr,qb);
  gemm_kproj <<<dim3(NB,6),256,0,stream>>>(yfe,Wkb,rsb,bk,bf,kproj);
  gemm_vprojT<<<dim3(NB,6),256,0,stream>>>(yfe,Wvb,rsb,bv,be,vprojT);
  attn_kernel<<<NBH,256,0,stream>>>(qb,kproj,vprojT,pout,ctxb);
  gemm_ring<1><<<dim3(200,3),512,0,stream>>>(ctxb,Wdb,bd,x,out);
  ln_kernel<<<NM,192,0,stream>>>(out,gamma,beta);
}